// Round 1
// 185.517 us; speedup vs baseline: 1.0056x; 1.0056x over previous
//
#include <hip/hip_runtime.h>
#include <math.h>

#define N_NODES 100000
#define E_EDGES 1600000
#define F_IN 32
#define HID 16
#define NC 10
#define SRC_BITS 17
#define SRC_MASK ((1u << SRC_BITS) - 1u)
#define VQ_SCALE 32767.0f
#define CBITS 8                  // bucket = 256 nodes (was 512)
#define BUCKET_N 256
#define NCB ((N_NODES + BUCKET_N - 1) / BUCKET_N)   // 391
#define BLK_E 2048               // edges per cnt/bucket block (was 8192)
#define NBLK ((E_EDGES + BLK_E - 1) / BLK_E)   // 782
#define NODE_GRID ((N_NODES + 255) / 256)      // 391

// bf16 pack (RNE) of two floats into one uint: low16 = lo, high16 = hi
__device__ __forceinline__ unsigned int bf16pair(float lo, float hi) {
    unsigned int ulo = __float_as_uint(lo), uhi = __float_as_uint(hi);
    ulo += 0x7fffu + ((ulo >> 16) & 1u);
    uhi += 0x7fffu + ((uhi >> 16) & 1u);
    return (ulo >> 16) | (uhi & 0xffff0000u);
}

__device__ __forceinline__ float lerp_pair(unsigned int pair, float v) {
    float a = __uint_as_float(pair << 16);
    float b = __uint_as_float(pair & 0xffff0000u);
    return fmaf(v, b - a, a);
}

// ------- fused: per-node layer-1 projections (blocks 0..390) + edge counts (391..1172) -------
__global__ __launch_bounds__(256) void fused_l1cnt(
    const float* __restrict__ x, const float* __restrict__ W1,
    const float* __restrict__ root1, const float* __restrict__ b1,
    const int* __restrict__ ei,
    unsigned int* __restrict__ y, float* __restrict__ r1,
    int* __restrict__ cnt)
{
    if (blockIdx.x >= NODE_GRID) {
        // ---- edge-count half: per-(block,bucket) histogram, int4 loads ----
        __shared__ int h[NCB];
        int b = blockIdx.x - NODE_GRID;
        for (int i = threadIdx.x; i < NCB; i += 256) h[i] = 0;
        __syncthreads();
        const int* dstp = ei + E_EDGES;
        int e0 = b * BLK_E;
        for (int i = threadIdx.x * 4; i < BLK_E; i += 1024) {
            int e = e0 + i;
            if (e + 3 < E_EDGES) {
                int4 d4 = *(const int4*)(dstp + e);
                atomicAdd(&h[d4.x >> CBITS], 1);
                atomicAdd(&h[d4.y >> CBITS], 1);
                atomicAdd(&h[d4.z >> CBITS], 1);
                atomicAdd(&h[d4.w >> CBITS], 1);
            } else {
                for (int k = 0; k < 4; k++)
                    if (e + k < E_EDGES) atomicAdd(&h[dstp[e + k] >> CBITS], 1);
            }
        }
        __syncthreads();
        for (int s = threadIdx.x; s < NCB; s += 256)
            cnt[(size_t)s * NBLK + b] = h[s];
        return;
    }
    // ---- node_l1 half ----
    __shared__ float sW0[F_IN * HID], sW1[F_IN * HID], sR[F_IN * HID], sB[HID];
    for (int i = threadIdx.x; i < F_IN * HID; i += 256) {
        sW0[i] = W1[i];
        sW1[i] = W1[F_IN * HID + i];
        sR[i]  = root1[i];
    }
    if (threadIdx.x < HID) sB[threadIdx.x] = b1[threadIdx.x];
    __syncthreads();

    int n = blockIdx.x * 256 + threadIdx.x;
    if (n >= N_NODES) return;

    float xr[F_IN];
    const float4* xp = (const float4*)(x + (size_t)n * F_IN);
    #pragma unroll
    for (int i = 0; i < F_IN / 4; i++) {
        float4 t = xp[i];
        xr[i*4+0] = t.x; xr[i*4+1] = t.y; xr[i*4+2] = t.z; xr[i*4+3] = t.w;
    }

    float a0[HID], a1[HID], ar[HID];
    #pragma unroll
    for (int o = 0; o < HID; o++) { a0[o] = 0.f; a1[o] = 0.f; ar[o] = sB[o]; }
    for (int i = 0; i < F_IN; i++) {
        float xi = xr[i];
        #pragma unroll
        for (int o = 0; o < HID; o++) {
            a0[o] += xi * sW0[i * HID + o];
            a1[o] += xi * sW1[i * HID + o];
            ar[o] += xi * sR[i * HID + o];
        }
    }
    unsigned int* py = y + (size_t)n * 16;
    float* pr = r1 + (size_t)n * HID;
    #pragma unroll
    for (int o = 0; o < HID; o++) {
        py[o] = bf16pair(a0[o], a1[o]);
        pr[o] = ar[o];
    }
}

// ---- row-wise exclusive prefix scan of cnt (one block per bucket row) ----
// Converts cnt[s][0..NBLK) from raw counts to exclusive prefix in place,
// writes total[s] = row sum. Removes the O(NBLK) serial walk from k_bucket.
__global__ __launch_bounds__(256) void k_rowscan(
    int* __restrict__ cnt, int* __restrict__ total)
{
    __shared__ int wsum[4], woff[4];
    int s = blockIdx.x;
    int t = threadIdx.x;
    int w = t >> 6, l = t & 63;
    int carry = 0;
    int* row = cnt + (size_t)s * NBLK;
    for (int c = 0; c < NBLK; c += 256) {
        int idx = c + t;
        int v = (idx < NBLK) ? row[idx] : 0;
        int incl = v;
        #pragma unroll
        for (int off = 1; off < 64; off <<= 1) {
            int u = __shfl_up(incl, off, 64);
            if (l >= off) incl += u;
        }
        if (l == 63) wsum[w] = incl;
        __syncthreads();
        if (t == 0) {
            int a = 0;
            #pragma unroll
            for (int i = 0; i < 4; i++) { woff[i] = a; a += wsum[i]; }
        }
        __syncthreads();
        int excl = woff[w] + incl - v;
        if (idx < NBLK) row[idx] = carry + excl;
        carry += woff[3] + wsum[3];
        __syncthreads();   // protect wsum/woff reuse next chunk
    }
    if (t == 0) total[s] = carry;
}

// ---- scatter into exact per-(block,bucket) windows — zero global atomics ----
// base[s] = (exclusive scan of bucket totals)[s] + rowprefix[s][blockIdx].
// Block 0 publishes bb[] (exclusive bucket bases) for k_bsort.
__global__ __launch_bounds__(512) void k_bucket(
    const int* __restrict__ ei, const float* __restrict__ ea,
    const int* __restrict__ cnt, const int* __restrict__ total,
    int2* __restrict__ ebuf, int* __restrict__ bb, int* __restrict__ start)
{
    __shared__ int wsum[8], woff[8];
    __shared__ int base[NCB], cur[NCB];
    int t = threadIdx.x;
    int tot = (t < NCB) ? total[t] : 0;
    // wave-shuffle exclusive scan of bucket totals (391 entries across 8 waves)
    int w = t >> 6, l = t & 63;
    int incl = tot;
    #pragma unroll
    for (int off = 1; off < 64; off <<= 1) {
        int u = __shfl_up(incl, off, 64);
        if (l >= off) incl += u;
    }
    if (l == 63) wsum[w] = incl;
    __syncthreads();
    if (t == 0) {
        int a = 0;
        #pragma unroll
        for (int i = 0; i < 8; i++) { woff[i] = a; a += wsum[i]; }
    }
    __syncthreads();
    int excl = woff[w] + incl - tot;
    if (t < NCB) {
        base[t] = excl + cnt[(size_t)t * NBLK + blockIdx.x];  // rowscan'd: exclusive prefix
        cur[t] = 0;
        if (blockIdx.x == 0) {
            bb[t] = excl;
            if (t == NCB - 1) { bb[NCB] = excl + tot; start[N_NODES] = E_EDGES; }
        }
    }
    __syncthreads();

    const int* dstp = ei + E_EDGES;
    int e0 = blockIdx.x * BLK_E;
    for (int i = t * 4; i < BLK_E; i += 2048) {
        int e = e0 + i;
        if (e + 3 < E_EDGES) {
            int4 d4 = *(const int4*)(dstp + e);
            int4 s4 = *(const int4*)(ei + e);
            float4 a4 = *(const float4*)(ea + e);
            {
                int s = d4.x >> CBITS;
                int off = atomicAdd(&cur[s], 1);
                unsigned int vq = (unsigned int)(a4.x * VQ_SCALE + 0.5f);
                ebuf[base[s] + off] = make_int2(d4.x & (BUCKET_N - 1),
                                               (int)((vq << SRC_BITS) | (unsigned int)s4.x));
            }
            {
                int s = d4.y >> CBITS;
                int off = atomicAdd(&cur[s], 1);
                unsigned int vq = (unsigned int)(a4.y * VQ_SCALE + 0.5f);
                ebuf[base[s] + off] = make_int2(d4.y & (BUCKET_N - 1),
                                               (int)((vq << SRC_BITS) | (unsigned int)s4.y));
            }
            {
                int s = d4.z >> CBITS;
                int off = atomicAdd(&cur[s], 1);
                unsigned int vq = (unsigned int)(a4.z * VQ_SCALE + 0.5f);
                ebuf[base[s] + off] = make_int2(d4.z & (BUCKET_N - 1),
                                               (int)((vq << SRC_BITS) | (unsigned int)s4.z));
            }
            {
                int s = d4.w >> CBITS;
                int off = atomicAdd(&cur[s], 1);
                unsigned int vq = (unsigned int)(a4.w * VQ_SCALE + 0.5f);
                ebuf[base[s] + off] = make_int2(d4.w & (BUCKET_N - 1),
                                               (int)((vq << SRC_BITS) | (unsigned int)s4.w));
            }
        } else {
            for (int k = 0; k < 4; k++) {
                int ee = e + k;
                if (ee >= E_EDGES) break;
                int dst = dstp[ee];
                int s = dst >> CBITS;
                int off = atomicAdd(&cur[s], 1);
                unsigned int vq = (unsigned int)(ea[ee] * VQ_SCALE + 0.5f);
                ebuf[base[s] + off] = make_int2(dst & (BUCKET_N - 1),
                                               (int)((vq << SRC_BITS) | (unsigned int)ei[ee]));
            }
        }
    }
}

// ---- per-bucket exact sort into es + start[]; 1024 threads; reads bb[] directly ----
__global__ __launch_bounds__(1024) void k_bsort(
    const int2* __restrict__ ebuf, const int* __restrict__ bb,
    unsigned int* __restrict__ es, int* __restrict__ start)
{
    __shared__ int hist[BUCKET_N];
    __shared__ int cursor[BUCKET_N];
    __shared__ int wsum[4], woff[4];
    int t = threadIdx.x;
    int b = blockIdx.x;
    int j0 = bb[b], j1 = bb[b + 1];
    if (t < BUCKET_N) { hist[t] = 0; cursor[t] = 0; }
    __syncthreads();
    for (int j = j0 + t; j < j1; j += 1024)
        atomicAdd(&hist[ebuf[j].x], 1);
    __syncthreads();
    int c = (t < BUCKET_N) ? hist[t] : 0;
    // wave-level inclusive scan over 256 node counts (first 4 waves)
    int w = t >> 6, l = t & 63;
    int incl = c;
    #pragma unroll
    for (int off = 1; off < 64; off <<= 1) {
        int u = __shfl_up(incl, off, 64);
        if (l >= off) incl += u;
    }
    if (w < 4 && l == 63) wsum[w] = incl;
    __syncthreads();
    if (t == 0) {
        int acc = 0;
        #pragma unroll
        for (int i = 0; i < 4; i++) { woff[i] = acc; acc += wsum[i]; }
    }
    __syncthreads();
    if (t < BUCKET_N) {
        int excl = woff[w] + incl - c;
        hist[t] = excl;                        // reuse as local start
        int node = (b << CBITS) + t;
        if (node < N_NODES) start[node] = j0 + excl;
    }
    __syncthreads();
    for (int j = j0 + t; j < j1; j += 1024) {
        int2 p = ebuf[j];
        int off = atomicAdd(&cursor[p.x], 1);
        es[j0 + hist[p.x] + off] = (unsigned int)p.y;
    }
}

// ------- Aggregation layer 1 + fused proj2: 16 lanes/node; 8-way unrolled gather -------
__global__ __launch_bounds__(256) void k_agg1(
    const unsigned int* __restrict__ es, const int* __restrict__ start,
    const unsigned int* __restrict__ y, const float* __restrict__ r1,
    const float* __restrict__ W2, const float* __restrict__ root2,
    const float* __restrict__ b2,
    unsigned int* __restrict__ z, float* __restrict__ r2)
{
    __shared__ float sh[16 * 17];          // h tile: 16 nodes x 16 comps (stride 17)
    __shared__ float sW0[HID * NC], sW1[HID * NC], sRt[HID * NC], sB2[NC];
    int t = threadIdx.x;
    if (t < HID * NC) { sW0[t] = W2[t]; sW1[t] = W2[HID * NC + t]; sRt[t] = root2[t]; }
    if (t >= HID * NC && t < HID * NC + NC) sB2[t - HID * NC] = b2[t - HID * NC];

    int idx = blockIdx.x * 256 + t;
    int n = idx >> 4, o = idx & 15, g = t >> 4;
    if (n < N_NODES) {
        int j0 = start[n], j1 = start[n + 1];
        float acc0 = 0.f, acc1 = 0.f, acc2 = 0.f, acc3 = 0.f;
        int j = j0;
        for (; j + 7 < j1; j += 8) {
            unsigned int p0 = es[j],   p1 = es[j+1], p2 = es[j+2], p3 = es[j+3];
            unsigned int p4 = es[j+4], p5 = es[j+5], p6 = es[j+6], p7 = es[j+7];
            unsigned int q0 = y[(size_t)(p0 & SRC_MASK) * 16 + o];
            unsigned int q1 = y[(size_t)(p1 & SRC_MASK) * 16 + o];
            unsigned int q2 = y[(size_t)(p2 & SRC_MASK) * 16 + o];
            unsigned int q3 = y[(size_t)(p3 & SRC_MASK) * 16 + o];
            unsigned int q4 = y[(size_t)(p4 & SRC_MASK) * 16 + o];
            unsigned int q5 = y[(size_t)(p5 & SRC_MASK) * 16 + o];
            unsigned int q6 = y[(size_t)(p6 & SRC_MASK) * 16 + o];
            unsigned int q7 = y[(size_t)(p7 & SRC_MASK) * 16 + o];
            acc0 += lerp_pair(q0, (float)(p0 >> SRC_BITS) * (1.0f / VQ_SCALE));
            acc1 += lerp_pair(q1, (float)(p1 >> SRC_BITS) * (1.0f / VQ_SCALE));
            acc2 += lerp_pair(q2, (float)(p2 >> SRC_BITS) * (1.0f / VQ_SCALE));
            acc3 += lerp_pair(q3, (float)(p3 >> SRC_BITS) * (1.0f / VQ_SCALE));
            acc0 += lerp_pair(q4, (float)(p4 >> SRC_BITS) * (1.0f / VQ_SCALE));
            acc1 += lerp_pair(q5, (float)(p5 >> SRC_BITS) * (1.0f / VQ_SCALE));
            acc2 += lerp_pair(q6, (float)(p6 >> SRC_BITS) * (1.0f / VQ_SCALE));
            acc3 += lerp_pair(q7, (float)(p7 >> SRC_BITS) * (1.0f / VQ_SCALE));
        }
        for (; j + 3 < j1; j += 4) {
            unsigned int p0 = es[j], p1 = es[j+1], p2 = es[j+2], p3 = es[j+3];
            unsigned int q0 = y[(size_t)(p0 & SRC_MASK) * 16 + o];
            unsigned int q1 = y[(size_t)(p1 & SRC_MASK) * 16 + o];
            unsigned int q2 = y[(size_t)(p2 & SRC_MASK) * 16 + o];
            unsigned int q3 = y[(size_t)(p3 & SRC_MASK) * 16 + o];
            acc0 += lerp_pair(q0, (float)(p0 >> SRC_BITS) * (1.0f / VQ_SCALE));
            acc1 += lerp_pair(q1, (float)(p1 >> SRC_BITS) * (1.0f / VQ_SCALE));
            acc2 += lerp_pair(q2, (float)(p2 >> SRC_BITS) * (1.0f / VQ_SCALE));
            acc3 += lerp_pair(q3, (float)(p3 >> SRC_BITS) * (1.0f / VQ_SCALE));
        }
        for (; j < j1; j++) {
            unsigned int p = es[j];
            unsigned int q = y[(size_t)(p & SRC_MASK) * 16 + o];
            acc0 += lerp_pair(q, (float)(p >> SRC_BITS) * (1.0f / VQ_SCALE));
        }
        float acc = (acc0 + acc1) + (acc2 + acc3);
        float inv = 1.0f / fmaxf((float)(j1 - j0), 1.0f);
        float hv = acc * inv + r1[(size_t)n * HID + o];
        sh[g * 17 + o] = hv > 0.0f ? hv : expm1f(hv);   // elu -> LDS
    }
    __syncthreads();

    // epilogue: same 16 lanes/node compute proj2 from the LDS h tile
    int n2 = blockIdx.x * 16 + g;
    if (n2 < N_NODES) {
        int cc = o;
        unsigned int* pz = z + (size_t)n2 * 16;
        if (cc < NC) {
            float a0 = 0.f, a1 = 0.f, ar = sB2[cc];
            #pragma unroll
            for (int i = 0; i < HID; i++) {
                float hi = sh[g * 17 + i];
                a0 += hi * sW0[i * NC + cc];
                a1 += hi * sW1[i * NC + cc];
                ar += hi * sRt[i * NC + cc];
            }
            pz[cc] = bf16pair(a0, a1);
            r2[(size_t)n2 * NC + cc] = ar;
        } else {
            pz[cc] = 0u;
        }
    }
}

// -- Aggregation layer 2: 16 lanes/node; 8-way unrolled; fused mean+root+log_softmax --
__global__ __launch_bounds__(256) void k_agg2(
    const unsigned int* __restrict__ es, const int* __restrict__ start,
    const unsigned int* __restrict__ z,
    const float* __restrict__ r2, float* __restrict__ out)
{
    int idx = blockIdx.x * 256 + threadIdx.x;
    int n = idx >> 4, o = idx & 15;
    if (n >= N_NODES) return;
    int j0 = start[n], j1 = start[n + 1];
    float acc0 = 0.f, acc1 = 0.f, acc2 = 0.f, acc3 = 0.f;
    int j = j0;
    for (; j + 7 < j1; j += 8) {
        unsigned int p0 = es[j],   p1 = es[j+1], p2 = es[j+2], p3 = es[j+3];
        unsigned int p4 = es[j+4], p5 = es[j+5], p6 = es[j+6], p7 = es[j+7];
        unsigned int q0 = z[(size_t)(p0 & SRC_MASK) * 16 + o];
        unsigned int q1 = z[(size_t)(p1 & SRC_MASK) * 16 + o];
        unsigned int q2 = z[(size_t)(p2 & SRC_MASK) * 16 + o];
        unsigned int q3 = z[(size_t)(p3 & SRC_MASK) * 16 + o];
        unsigned int q4 = z[(size_t)(p4 & SRC_MASK) * 16 + o];
        unsigned int q5 = z[(size_t)(p5 & SRC_MASK) * 16 + o];
        unsigned int q6 = z[(size_t)(p6 & SRC_MASK) * 16 + o];
        unsigned int q7 = z[(size_t)(p7 & SRC_MASK) * 16 + o];
        acc0 += lerp_pair(q0, (float)(p0 >> SRC_BITS) * (1.0f / VQ_SCALE));
        acc1 += lerp_pair(q1, (float)(p1 >> SRC_BITS) * (1.0f / VQ_SCALE));
        acc2 += lerp_pair(q2, (float)(p2 >> SRC_BITS) * (1.0f / VQ_SCALE));
        acc3 += lerp_pair(q3, (float)(p3 >> SRC_BITS) * (1.0f / VQ_SCALE));
        acc0 += lerp_pair(q4, (float)(p4 >> SRC_BITS) * (1.0f / VQ_SCALE));
        acc1 += lerp_pair(q5, (float)(p5 >> SRC_BITS) * (1.0f / VQ_SCALE));
        acc2 += lerp_pair(q6, (float)(p6 >> SRC_BITS) * (1.0f / VQ_SCALE));
        acc3 += lerp_pair(q7, (float)(p7 >> SRC_BITS) * (1.0f / VQ_SCALE));
    }
    for (; j + 3 < j1; j += 4) {
        unsigned int p0 = es[j], p1 = es[j+1], p2 = es[j+2], p3 = es[j+3];
        unsigned int q0 = z[(size_t)(p0 & SRC_MASK) * 16 + o];
        unsigned int q1 = z[(size_t)(p1 & SRC_MASK) * 16 + o];
        unsigned int q2 = z[(size_t)(p2 & SRC_MASK) * 16 + o];
        unsigned int q3 = z[(size_t)(p3 & SRC_MASK) * 16 + o];
        acc0 += lerp_pair(q0, (float)(p0 >> SRC_BITS) * (1.0f / VQ_SCALE));
        acc1 += lerp_pair(q1, (float)(p1 >> SRC_BITS) * (1.0f / VQ_SCALE));
        acc2 += lerp_pair(q2, (float)(p2 >> SRC_BITS) * (1.0f / VQ_SCALE));
        acc3 += lerp_pair(q3, (float)(p3 >> SRC_BITS) * (1.0f / VQ_SCALE));
    }
    for (; j < j1; j++) {
        unsigned int p = es[j];
        unsigned int q = z[(size_t)(p & SRC_MASK) * 16 + o];
        acc0 += lerp_pair(q, (float)(p >> SRC_BITS) * (1.0f / VQ_SCALE));
    }
    float acc = (acc0 + acc1) + (acc2 + acc3);
    float val = -INFINITY;
    if (o < NC) {
        float inv = 1.0f / fmaxf((float)(j1 - j0), 1.0f);
        val = acc * inv + r2[(size_t)n * NC + o];
    }
    float mx = val;
    #pragma unroll
    for (int off = 8; off > 0; off >>= 1) mx = fmaxf(mx, __shfl_xor(mx, off, 16));
    float ex = (o < NC) ? expf(val - mx) : 0.0f;
    float ssum = ex;
    #pragma unroll
    for (int off = 8; off > 0; off >>= 1) ssum += __shfl_xor(ssum, off, 16);
    if (o < NC) out[(size_t)n * NC + o] = val - mx - logf(ssum);
}

extern "C" void kernel_launch(void* const* d_in, const int* in_sizes, int n_in,
                              void* d_out, int out_size, void* d_ws, size_t ws_size,
                              hipStream_t stream) {
    const float* x     = (const float*)d_in[0];
    const int*   ei    = (const int*)d_in[1];     // [2,E] src row then dst row
    const float* ea    = (const float*)d_in[2];   // [E,1]
    const float* W1    = (const float*)d_in[3];
    const float* root1 = (const float*)d_in[4];
    const float* b1    = (const float*)d_in[5];
    const float* W2    = (const float*)d_in[6];
    const float* root2 = (const float*)d_in[7];
    const float* b2    = (const float*)d_in[8];
    float* out = (float*)d_out;

    // Workspace layout (all offsets 16B-aligned).
    char* wsb = (char*)d_ws;
    int2*         ebuf   = (int2*)wsb;                                    // E int2 = 12.8MB
    unsigned int* es     = (unsigned int*)(wsb + (size_t)E_EDGES * 8);    // E * 4B
    unsigned int* y      = es + (size_t)E_EDGES;                          // 100k*16*4B
    float*        r1     = (float*)(y + (size_t)N_NODES * 16);            // 100k*16*4B
    unsigned int* z      = (unsigned int*)(r1 + (size_t)N_NODES * HID);   // 100k*16*4B
    float*        r2     = (float*)(z + (size_t)N_NODES * 16);            // 100k*10*4B
    int*          start  = (int*)(r2 + (size_t)N_NODES * NC);             // N+1
    int*          cnt    = start + N_NODES + 1;                           // NCB*NBLK prefix table
    int*          total  = cnt + (size_t)NCB * NBLK;                      // NCB row totals
    int*          bb     = total + NCB;                                   // NCB+1 bucket bases

    int aggGrid  = (N_NODES * 16 + 255) / 256;

    fused_l1cnt<<<NODE_GRID + NBLK, 256, 0, stream>>>(x, W1, root1, b1, ei, y, r1, cnt);
    k_rowscan<<<NCB, 256, 0, stream>>>(cnt, total);
    k_bucket<<<NBLK, 512, 0, stream>>>(ei, ea, cnt, total, ebuf, bb, start);
    k_bsort <<<NCB, 1024, 0, stream>>>(ebuf, bb, es, start);
    k_agg1  <<<aggGrid, 256, 0, stream>>>(es, start, y, r1, W2, root2, b2, z, r2);
    k_agg2  <<<aggGrid, 256, 0, stream>>>(es, start, z, r2, out);
}